// Round 4
// baseline (1190.428 us; speedup 1.0000x reference)
//
#include <hip/hip_runtime.h>
#include <math.h>

#define D 256
#define HD 3
#define NEG_SLOPE 0.2f

// ---------------------------------------------------------------------------
// GEMM: for head h: hs = h @ Ws[h]^T  -> written straight into d_out[n, h*D+d]
//                   z  = h @ Wf[h]^T  -> workspace zbuf[h][n][d]
// C[n,d] = sum_k A[n,k] * W[d,k]  (both k-contiguous -> coalesced float4 loads)
// 128x128 tile, BK=16, 256 threads, 8x8 microtile SPLIT as 2x2 blocks of 4x4:
// thread rows {4(tid&15)+i, 64+4(tid&15)+i}, cols {4(tid>>4)+j, 64+4(tid>>4)+j}.
// This makes every ds_read_b128 16B-strided -> <=2 addresses/bank (free),
// vs the contiguous-8 layout whose 32B stride was a 4-way bank conflict.
// Register-double-buffered global staging (prefetch k+1 during k's FMAs).
// ---------------------------------------------------------------------------
#define BM 128
#define BK 16

__global__ __launch_bounds__(256) void gemm_kernel(
    const float* __restrict__ hin, const float* __restrict__ Wself,
    const float* __restrict__ Wfunc, float* __restrict__ out,
    float* __restrict__ zbuf, int Nn)
{
  const int head = blockIdx.z >> 1;
  const int isF  = blockIdx.z & 1;
  const float* __restrict__ W = (isF ? Wfunc : Wself) + (size_t)head * D * D;
  const int row0 = blockIdx.y * BM;   // y = row tile (slow dim)
  const int col0 = blockIdx.x * BM;   // x = col tile (fast dim; shares A-stripe)

  __shared__ float As[BK][BM + 4];
  __shared__ float Bs[BK][BM + 4];

  const int tid = threadIdx.x;
  const int ra = (tid & 15) * 4;    // this thread's low row quad
  const int cb = (tid >> 4) * 4;    // this thread's low col quad
  const int lrow = tid >> 2;        // loader row (0..63; +64 for second half)
  const int lk = (tid & 3) << 2;    // loader k offset (0,4,8,12)

  float acc[8][8];
#pragma unroll
  for (int i = 0; i < 8; ++i)
#pragma unroll
    for (int j = 0; j < 8; ++j) acc[i][j] = 0.f;

  const int ar0 = row0 + lrow, ar1 = row0 + 64 + lrow;
  const bool ok0 = ar0 < Nn, ok1 = ar1 < Nn;
  const float* ap0 = hin + (size_t)(ok0 ? ar0 : 0) * D + lk;
  const float* ap1 = hin + (size_t)(ok1 ? ar1 : 0) * D + lk;
  const float* bp0 = W + (size_t)(col0 + lrow) * D + lk;
  const float* bp1 = W + (size_t)(col0 + 64 + lrow) * D + lk;

  // prologue: fetch tile 0
  float4 a0 = *(const float4*)(ap0);
  float4 a1 = *(const float4*)(ap1);
  float4 b0 = *(const float4*)(bp0);
  float4 b1 = *(const float4*)(bp1);
  if (!ok0) a0 = make_float4(0.f, 0.f, 0.f, 0.f);
  if (!ok1) a1 = make_float4(0.f, 0.f, 0.f, 0.f);

  for (int k0 = 0; k0 < D; k0 += BK) {
    // store current tile to LDS (transposed k-major; <=2-way banks on writes)
    As[lk + 0][lrow] = a0.x; As[lk + 1][lrow] = a0.y;
    As[lk + 2][lrow] = a0.z; As[lk + 3][lrow] = a0.w;
    As[lk + 0][64 + lrow] = a1.x; As[lk + 1][64 + lrow] = a1.y;
    As[lk + 2][64 + lrow] = a1.z; As[lk + 3][64 + lrow] = a1.w;
    Bs[lk + 0][lrow] = b0.x; Bs[lk + 1][lrow] = b0.y;
    Bs[lk + 2][lrow] = b0.z; Bs[lk + 3][lrow] = b0.w;
    Bs[lk + 0][64 + lrow] = b1.x; Bs[lk + 1][64 + lrow] = b1.y;
    Bs[lk + 2][64 + lrow] = b1.z; Bs[lk + 3][64 + lrow] = b1.w;
    __syncthreads();

    // prefetch next tile into registers (latency hides under FMAs below)
    const int kn = k0 + BK;
    if (kn < D) {
      a0 = *(const float4*)(ap0 + kn);
      a1 = *(const float4*)(ap1 + kn);
      b0 = *(const float4*)(bp0 + kn);
      b1 = *(const float4*)(bp1 + kn);
      if (!ok0) a0 = make_float4(0.f, 0.f, 0.f, 0.f);
      if (!ok1) a1 = make_float4(0.f, 0.f, 0.f, 0.f);
    }

#pragma unroll
    for (int k = 0; k < BK; ++k) {
      float a[8], b[8];
      *(float4*)&a[0] = *(const float4*)&As[k][ra];
      *(float4*)&a[4] = *(const float4*)&As[k][64 + ra];
      *(float4*)&b[0] = *(const float4*)&Bs[k][cb];
      *(float4*)&b[4] = *(const float4*)&Bs[k][64 + cb];
#pragma unroll
      for (int i = 0; i < 8; ++i)
#pragma unroll
        for (int j = 0; j < 8; ++j) acc[i][j] += a[i] * b[j];
    }
    __syncthreads();
  }

  // epilogue: acc[i][j] -> row (i<4 ? ra+i : 64+ra+i-4), col (j<4 ? cb+j : 64+cb+j-4)
  float* base;
  size_t rstride;
  if (isF) { base = zbuf + (size_t)head * Nn * D; rstride = D; }
  else     { base = out + (size_t)head * D;       rstride = HD * D; }
#pragma unroll
  for (int i = 0; i < 8; ++i) {
    int r = row0 + (i < 4 ? ra + i : 64 + ra + (i - 4));
    if (r < Nn) {
      float* p = base + (size_t)r * rstride + col0;
      *(float4*)(p + cb)      = make_float4(acc[i][0], acc[i][1], acc[i][2], acc[i][3]);
      *(float4*)(p + 64 + cb) = make_float4(acc[i][4], acc[i][5], acc[i][6], acc[i][7]);
    }
  }
}

// ---------------------------------------------------------------------------
// Per-(node,head) scalars: zs = z . a_src, zd = z . a_dst.  One wave each.
// ---------------------------------------------------------------------------
__global__ __launch_bounds__(256) void node_dot_kernel(
    const float* __restrict__ zbuf, const float* __restrict__ attn,
    float* __restrict__ zs, float* __restrict__ zd, int Nn)
{
  int wid  = blockIdx.x * 4 + (threadIdx.x >> 6);
  int lane = threadIdx.x & 63;
  if (wid >= Nn * HD) return;
  int n = wid / HD, h = wid - n * HD;
  const float* zr = zbuf + ((size_t)h * Nn + n) * D;
  float4 v  = *(const float4*)&zr[lane * 4];
  float4 as = *(const float4*)&attn[h * 3 * D + lane * 4];
  float4 ad = *(const float4*)&attn[h * 3 * D + D + lane * 4];
  float ps = v.x * as.x + v.y * as.y + v.z * as.z + v.w * as.w;
  float pd = v.x * ad.x + v.y * ad.y + v.z * ad.z + v.w * ad.w;
#pragma unroll
  for (int off = 32; off; off >>= 1) {
    ps += __shfl_down(ps, off);
    pd += __shfl_down(pd, off);
  }
  if (lane == 0) { zs[(size_t)h * Nn + n] = ps; zd[(size_t)h * Nn + n] = pd; }
}

// ---------------------------------------------------------------------------
// Per-edge: ew = edge_w . a_w (3 heads), e = leaky(zs[src]+zd[dst]+ew),
// plus dst-degree histogram for CSR.  One wave per edge.
// ---------------------------------------------------------------------------
__global__ __launch_bounds__(256) void edge_kernel(
    const float* __restrict__ edge_w, const float* __restrict__ attn,
    const int* __restrict__ src, const int* __restrict__ dst,
    const float* __restrict__ zs, const float* __restrict__ zd,
    float* __restrict__ e_score, int* __restrict__ counts, int E_, int Nn)
{
  int e    = blockIdx.x * 4 + (threadIdx.x >> 6);
  int lane = threadIdx.x & 63;
  if (e >= E_) return;
  float4 v = *(const float4*)&edge_w[(size_t)e * D + lane * 4];
  float p[HD];
#pragma unroll
  for (int h = 0; h < HD; ++h) {
    float4 aw = *(const float4*)&attn[h * 3 * D + 2 * D + lane * 4];
    p[h] = v.x * aw.x + v.y * aw.y + v.z * aw.z + v.w * aw.w;
  }
#pragma unroll
  for (int off = 32; off; off >>= 1) {
    p[0] += __shfl_down(p[0], off);
    p[1] += __shfl_down(p[1], off);
    p[2] += __shfl_down(p[2], off);
  }
  if (lane == 0) {
    int s = src[e], d = dst[e];
#pragma unroll
    for (int h = 0; h < HD; ++h) {
      float sc = zs[(size_t)h * Nn + s] + zd[(size_t)h * Nn + d] + p[h];
      sc = sc > 0.f ? sc : NEG_SLOPE * sc;
      e_score[(size_t)h * E_ + e] = sc;
    }
    atomicAdd(&counts[d], 1);
  }
}

// ---------------------------------------------------------------------------
// Single-block exclusive scan of counts -> offsets (and cursor copy).
// ---------------------------------------------------------------------------
__global__ __launch_bounds__(1024) void scan_kernel(
    const int* __restrict__ counts, int* __restrict__ offsets,
    int* __restrict__ cursor, int Nn, int chunk)
{
  __shared__ int part[1024];
  int tid = threadIdx.x;
  int b = tid * chunk;
  int e = b + chunk; if (e > Nn) e = Nn;
  int sum = 0;
  for (int i = b; i < e; ++i) sum += counts[i];
  part[tid] = sum;
  __syncthreads();
  for (int off = 1; off < 1024; off <<= 1) {
    int v = (tid >= off) ? part[tid - off] : 0;
    __syncthreads();
    part[tid] += v;
    __syncthreads();
  }
  int run = (tid > 0) ? part[tid - 1] : 0;
  for (int i = b; i < e; ++i) {
    offsets[i] = run; cursor[i] = run; run += counts[i];
  }
  if (tid == 1023) offsets[Nn] = part[1023];
}

// ---------------------------------------------------------------------------
// CSR fill: edge_ids grouped by dst.
// ---------------------------------------------------------------------------
__global__ __launch_bounds__(256) void fill_kernel(
    const int* __restrict__ dst, int* __restrict__ cursor,
    int* __restrict__ edge_ids, int E_)
{
  int e = blockIdx.x * 256 + threadIdx.x;
  if (e < E_) {
    int p = atomicAdd(&cursor[dst[e]], 1);
    edge_ids[p] = e;
  }
}

// ---------------------------------------------------------------------------
// Per-(node,head): softmax over incoming edges + weighted gather of z[src],
// epilogue out = h + relu(hs + agg).  One 256-thread block per (n, head);
// thread t owns channel t.  No atomics.  Gather loop software-prefetches the
// next edge's indices to break the 3-deep dependent load chain.
// ---------------------------------------------------------------------------
__global__ __launch_bounds__(256) void agg_kernel(
    const float* __restrict__ zbuf, const float* __restrict__ e_score,
    const int* __restrict__ src, const int* __restrict__ offsets,
    const int* __restrict__ edge_ids, const float* __restrict__ hin,
    float* __restrict__ out, int Nn, int E_)
{
  const int n = blockIdx.x, head = blockIdx.y;
  const int tid = threadIdx.x, lane = tid & 63, w = tid >> 6;
  __shared__ float red[4];
  const int s = offsets[n];
  const int deg = offsets[n + 1] - s;
  const float* sc = e_score + (size_t)head * E_;

  float lm = -INFINITY;
  for (int i = tid; i < deg; i += 256) lm = fmaxf(lm, sc[edge_ids[s + i]]);
#pragma unroll
  for (int off = 32; off; off >>= 1) lm = fmaxf(lm, __shfl_down(lm, off));
  if (lane == 0) red[w] = lm;
  __syncthreads();
  float m = fmaxf(fmaxf(red[0], red[1]), fmaxf(red[2], red[3]));
  if (!isfinite(m)) m = 0.f;          // empty segment -> segment_max fixup
  __syncthreads();

  float ls = 0.f;
  for (int i = tid; i < deg; i += 256) ls += __expf(sc[edge_ids[s + i]] - m);
#pragma unroll
  for (int off = 32; off; off >>= 1) ls += __shfl_down(ls, off);
  if (lane == 0) red[w] = ls;
  __syncthreads();
  float den = red[0] + red[1] + red[2] + red[3];
  float inv = 1.f / fmaxf(den, 1e-16f);

  float acc = 0.f;
  const float* zh = zbuf + (size_t)head * Nn * D;
  if (deg > 0) {
    int e_cur = edge_ids[s];
    int s_cur = src[e_cur];
    float sc_cur = sc[e_cur];
    for (int i = 0; i < deg; ++i) {
      int e_nxt = 0, s_nxt = 0; float sc_nxt = 0.f;
      if (i + 1 < deg) {                 // prefetch next edge's metadata
        e_nxt = edge_ids[s + i + 1];
        s_nxt = src[e_nxt];
        sc_nxt = sc[e_nxt];
      }
      float wgt = __expf(sc_cur - m) * inv;
      acc += wgt * zh[(size_t)s_cur * D + tid];
      e_cur = e_nxt; s_cur = s_nxt; sc_cur = sc_nxt;
    }
  }
  size_t o = (size_t)n * (HD * D) + head * D + tid;
  out[o] = hin[(size_t)n * D + tid] + fmaxf(out[o] + acc, 0.f);
}

// ---------------------------------------------------------------------------
extern "C" void kernel_launch(void* const* d_in, const int* in_sizes, int n_in,
                              void* d_out, int out_size, void* d_ws, size_t ws_size,
                              hipStream_t stream) {
  const float* hin    = (const float*)d_in[0];
  const float* edge_w = (const float*)d_in[1];
  const int*   src    = (const int*)d_in[2];
  const int*   dst    = (const int*)d_in[3];
  const float* Wself  = (const float*)d_in[4];
  const float* Wfunc  = (const float*)d_in[5];
  const float* attn   = (const float*)d_in[6];
  float* out = (float*)d_out;

  const int Nn = in_sizes[0] / D;   // 20000
  const int E_ = in_sizes[2];       // 320000

  // workspace layout
  float* zbuf    = (float*)d_ws;                    // H*N*D
  float* zs      = zbuf + (size_t)HD * Nn * D;      // H*N
  float* zd      = zs + (size_t)HD * Nn;            // H*N
  float* e_score = zd + (size_t)HD * Nn;            // H*E
  int*   counts   = (int*)(e_score + (size_t)HD * E_); // N
  int*   offsets  = counts + Nn;                    // N+1
  int*   cursor   = offsets + Nn + 1;               // N
  int*   edge_ids = cursor + Nn;                    // E

  hipMemsetAsync(counts, 0, (size_t)Nn * sizeof(int), stream);

  dim3 ggrid(D / BM, (Nn + BM - 1) / BM, 2 * HD);   // x=col (fast), y=row
  gemm_kernel<<<ggrid, 256, 0, stream>>>(hin, Wself, Wfunc, out, zbuf, Nn);

  int nwave = Nn * HD;
  node_dot_kernel<<<(nwave + 3) / 4, 256, 0, stream>>>(zbuf, attn, zs, zd, Nn);

  edge_kernel<<<(E_ + 3) / 4, 256, 0, stream>>>(edge_w, attn, src, dst, zs, zd,
                                                e_score, counts, E_, Nn);

  int chunk = (Nn + 1023) / 1024;
  scan_kernel<<<1, 1024, 0, stream>>>(counts, offsets, cursor, Nn, chunk);

  fill_kernel<<<(E_ + 255) / 256, 256, 0, stream>>>(dst, cursor, edge_ids, E_);

  dim3 agrid(Nn, HD);
  agg_kernel<<<agrid, 256, 0, stream>>>(zbuf, e_score, src, offsets, edge_ids,
                                        hin, out, Nn, E_);
}

// Round 9
// 898.006 us; speedup vs baseline: 1.3256x; 1.3256x over previous
//
#include <hip/hip_runtime.h>
#include <math.h>

#define D 256
#define HD 3
#define NEG_SLOPE 0.2f

typedef __attribute__((ext_vector_type(8))) short bfrag;   // 8 bf16 = 4 VGPR
typedef __attribute__((ext_vector_type(4))) float f32x4;   // mfma 16x16 acc

// RNE f32 -> bf16 hi/lo split helper (4 elems, base is compile-time 0 or 4).
__device__ __forceinline__ void cvt4(float4 x, int base, bfrag& hi, bfrag& lo) {
  float v[4] = {x.x, x.y, x.z, x.w};
#pragma unroll
  for (int j = 0; j < 4; ++j) {
    unsigned u = __float_as_uint(v[j]);
    unsigned hr = (u + 0x7FFFu + ((u >> 16) & 1u)) >> 16;
    float hf = __uint_as_float(hr << 16);
    float d = v[j] - hf;
    unsigned ul = __float_as_uint(d);
    unsigned lr = (ul + 0x7FFFu + ((ul >> 16) & 1u)) >> 16;
    hi[base + j] = (short)hr;
    lo[base + j] = (short)lr;
  }
}

// ---------------------------------------------------------------------------
// W split: fp32 -> bf16 hi/lo, K-CHUNK-MAJOR Wsp[6][2][8][256][32]
// (matrix y = head*2+isF, part 0=hi; chunk c=k>>5 holds rows n x (k&31)).
// GEMM staging of one K-step then reads a contiguous 16KB block.
// ---------------------------------------------------------------------------
__global__ __launch_bounds__(256) void splitW_kernel(
    const float* __restrict__ Wself, const float* __restrict__ Wfunc,
    ushort* __restrict__ Wsp)
{
  int idx = blockIdx.x * 256 + threadIdx.x;      // 0 .. 6*65536-1
  int y = idx >> 16, off = idx & 65535;
  const float* srcm = ((y & 1) ? Wfunc : Wself) + (size_t)(y >> 1) * 65536;
  float x = srcm[off];
  unsigned u = __float_as_uint(x);
  unsigned hr = (u + 0x7FFFu + ((u >> 16) & 1u)) >> 16;
  float hf = __uint_as_float(hr << 16);
  float dlt = x - hf;
  unsigned ul = __float_as_uint(dlt);
  unsigned lr = (ul + 0x7FFFu + ((ul >> 16) & 1u)) >> 16;
  int n = off >> 8, k = off & 255;
  size_t kidx = (size_t)(k >> 5) * 8192 + (size_t)n * 32 + (k & 31);
  Wsp[(size_t)y * 131072 + kidx]         = (ushort)hr;
  Wsp[(size_t)y * 131072 + 65536 + kidx] = (ushort)lr;
}

// ---------------------------------------------------------------------------
// MFMA GEMM (bf16 x3 split): C[n,d] = sum_k A[n,k] W[d,k] for 6 matrices.
// C = AhiWhi + AloWhi + AhiWlo (dropped AloWlo ~2^-16 rel).  A is split
// ON THE FLY from fp32 (same 32B/lane global traffic as a precomputed
// hi/lo pair; conversion VALU hides under MFMA on the separate pipe).
// Block = 256 thr / 4 waves; tile 128 rows x 256 cols; K-step 32.
// Per K-step: stage W chunk (contiguous 16KB x2) in LDS with chunk-XOR
// swizzle (8 lanes per 4-bank group on write AND read).
// 16 n-tiles x 2 m-tiles x 3 products = 96 MFMA / wave / K-step.
// mfma_f32_16x16x32_bf16: A lane: row=lane&15, k=(lane>>4)*8+j;
// B lane: col=lane&15, k same; C/D: col=lane&15, row=(lane>>4)*4+reg [m89].
// ---------------------------------------------------------------------------
__global__ __launch_bounds__(256) void gemm_mfma_kernel(
    const float* __restrict__ hin, const ushort* __restrict__ Wsp,
    float* __restrict__ out, float* __restrict__ zbuf, int Nn)
{
  const int mIdx = blockIdx.y;
  const int head = mIdx >> 1, isF = mIdx & 1;
  __shared__ ushort Wlds[2][8192];       // [part][n=256][k=32] ushort, 32 KB
  const int tid = threadIdx.x;
  const int lane = tid & 63, wv = tid >> 6;
  const int m = lane & 15, kg = lane >> 4;
  const int wswz = (kg ^ ((m >> 1) & 3)) * 8;   // read-side chunk swizzle
  const int tswz = (tid >> 1) & 3;              // write-side chunk swizzle

  f32x4 acc[2][16];
#pragma unroll
  for (int i = 0; i < 2; ++i)
#pragma unroll
    for (int j = 0; j < 16; ++j) acc[i][j] = (f32x4){0.f, 0.f, 0.f, 0.f};

  const int rowA0 = blockIdx.x * 128 + wv * 32 + m;
  const int rowA1 = rowA0 + 16;
  const float* ap0 = hin + (size_t)min(rowA0, Nn - 1) * 256; // clamp; masked at store
  const float* ap1 = hin + (size_t)min(rowA1, Nn - 1) * 256;
  // k-chunk-major W: chunk block = 8192 ushorts; thread tid owns row n=tid.
  const ushort* wsrc_h = Wsp + (size_t)mIdx * 131072 + (size_t)tid * 32;
  const ushort* wsrc_l = wsrc_h + 65536;

  for (int k0 = 0; k0 < 256; k0 += 32) {
    // stage W chunk: contiguous 16KB block per part, chunk-XOR swizzled
#pragma unroll
    for (int c = 0; c < 4; ++c) {
      uint4 vh = *(const uint4*)(wsrc_h + (size_t)k0 * 256 + c * 8);
      uint4 vl = *(const uint4*)(wsrc_l + (size_t)k0 * 256 + c * 8);
      int pos = tid * 32 + ((c ^ tswz) * 8);
      *(uint4*)&Wlds[0][pos] = vh;
      *(uint4*)&Wlds[1][pos] = vl;
    }
    // A fragments: 8 consecutive fp32 per row (32B/lane), split in-register
    float4 x00 = *(const float4*)(ap0 + k0 + kg * 8);
    float4 x01 = *(const float4*)(ap0 + k0 + kg * 8 + 4);
    float4 x10 = *(const float4*)(ap1 + k0 + kg * 8);
    float4 x11 = *(const float4*)(ap1 + k0 + kg * 8 + 4);
    __syncthreads();
    bfrag ah0, al0, ah1, al1;
    cvt4(x00, 0, ah0, al0); cvt4(x01, 4, ah0, al0);
    cvt4(x10, 0, ah1, al1); cvt4(x11, 4, ah1, al1);
#pragma unroll
    for (int nt = 0; nt < 16; ++nt) {
      const int wp = (nt * 16 + m) * 32 + wswz;
      bfrag wh = *(const bfrag*)&Wlds[0][wp];
      bfrag wl = *(const bfrag*)&Wlds[1][wp];
      acc[0][nt] = __builtin_amdgcn_mfma_f32_16x16x32_bf16(ah0, wh, acc[0][nt], 0, 0, 0);
      acc[1][nt] = __builtin_amdgcn_mfma_f32_16x16x32_bf16(ah1, wh, acc[1][nt], 0, 0, 0);
      acc[0][nt] = __builtin_amdgcn_mfma_f32_16x16x32_bf16(al0, wh, acc[0][nt], 0, 0, 0);
      acc[1][nt] = __builtin_amdgcn_mfma_f32_16x16x32_bf16(al1, wh, acc[1][nt], 0, 0, 0);
      acc[0][nt] = __builtin_amdgcn_mfma_f32_16x16x32_bf16(ah0, wl, acc[0][nt], 0, 0, 0);
      acc[1][nt] = __builtin_amdgcn_mfma_f32_16x16x32_bf16(ah1, wl, acc[1][nt], 0, 0, 0);
    }
    __syncthreads();
  }

  // epilogue: C row = base + (lane>>4)*4 + r, col = nt*16 + (lane&15)
  const int rb = blockIdx.x * 128 + wv * 32 + kg * 4;
  float* basep;
  size_t rstride;
  if (isF) { basep = zbuf + (size_t)head * Nn * 256; rstride = 256; }
  else     { basep = out + (size_t)head * 256;       rstride = HD * D; }
#pragma unroll
  for (int mt = 0; mt < 2; ++mt)
#pragma unroll
    for (int r = 0; r < 4; ++r) {
      int row = rb + mt * 16 + r;
      if (row < Nn) {
        float* po = basep + (size_t)row * rstride;
#pragma unroll
        for (int nt = 0; nt < 16; ++nt)
          po[nt * 16 + m] = acc[mt][nt][r];
      }
    }
}

// ---------------------------------------------------------------------------
// Per-(node,head) scalars: zs = z . a_src, zd = z . a_dst.  One wave each.
// ---------------------------------------------------------------------------
__global__ __launch_bounds__(256) void node_dot_kernel(
    const float* __restrict__ zbuf, const float* __restrict__ attn,
    float* __restrict__ zs, float* __restrict__ zd, int Nn)
{
  int wid  = blockIdx.x * 4 + (threadIdx.x >> 6);
  int lane = threadIdx.x & 63;
  if (wid >= Nn * HD) return;
  int n = wid / HD, h = wid - n * HD;
  const float* zr = zbuf + ((size_t)h * Nn + n) * D;
  float4 v  = *(const float4*)&zr[lane * 4];
  float4 as = *(const float4*)&attn[h * 3 * D + lane * 4];
  float4 ad = *(const float4*)&attn[h * 3 * D + D + lane * 4];
  float ps = v.x * as.x + v.y * as.y + v.z * as.z + v.w * as.w;
  float pd = v.x * ad.x + v.y * ad.y + v.z * ad.z + v.w * ad.w;
#pragma unroll
  for (int off = 32; off; off >>= 1) {
    ps += __shfl_down(ps, off);
    pd += __shfl_down(pd, off);
  }
  if (lane == 0) { zs[(size_t)h * Nn + n] = ps; zd[(size_t)h * Nn + n] = pd; }
}

// ---------------------------------------------------------------------------
// Per-edge: ew = edge_w . a_w (3 heads), e = leaky(zs[src]+zd[dst]+ew),
// plus dst-degree histogram for CSR.  One wave per edge.
// ---------------------------------------------------------------------------
__global__ __launch_bounds__(256) void edge_kernel(
    const float* __restrict__ edge_w, const float* __restrict__ attn,
    const int* __restrict__ src, const int* __restrict__ dst,
    const float* __restrict__ zs, const float* __restrict__ zd,
    float* __restrict__ e_score, int* __restrict__ counts, int E_, int Nn)
{
  int e    = blockIdx.x * 4 + (threadIdx.x >> 6);
  int lane = threadIdx.x & 63;
  if (e >= E_) return;
  float4 v = *(const float4*)&edge_w[(size_t)e * D + lane * 4];
  float p[HD];
#pragma unroll
  for (int h = 0; h < HD; ++h) {
    float4 aw = *(const float4*)&attn[h * 3 * D + 2 * D + lane * 4];
    p[h] = v.x * aw.x + v.y * aw.y + v.z * aw.z + v.w * aw.w;
  }
#pragma unroll
  for (int off = 32; off; off >>= 1) {
    p[0] += __shfl_down(p[0], off);
    p[1] += __shfl_down(p[1], off);
    p[2] += __shfl_down(p[2], off);
  }
  if (lane == 0) {
    int s = src[e], d = dst[e];
#pragma unroll
    for (int h = 0; h < HD; ++h) {
      float sc = zs[(size_t)h * Nn + s] + zd[(size_t)h * Nn + d] + p[h];
      sc = sc > 0.f ? sc : NEG_SLOPE * sc;
      e_score[(size_t)h * E_ + e] = sc;
    }
    atomicAdd(&counts[d], 1);
  }
}

// ---------------------------------------------------------------------------
// Single-block exclusive scan of counts -> offsets (and cursor copy).
// ---------------------------------------------------------------------------
__global__ __launch_bounds__(1024) void scan_kernel(
    const int* __restrict__ counts, int* __restrict__ offsets,
    int* __restrict__ cursor, int Nn, int chunk)
{
  __shared__ int part[1024];
  int tid = threadIdx.x;
  int b = tid * chunk;
  int e = b + chunk; if (e > Nn) e = Nn;
  int sum = 0;
  for (int i = b; i < e; ++i) sum += counts[i];
  part[tid] = sum;
  __syncthreads();
  for (int off = 1; off < 1024; off <<= 1) {
    int v = (tid >= off) ? part[tid - off] : 0;
    __syncthreads();
    part[tid] += v;
    __syncthreads();
  }
  int run = (tid > 0) ? part[tid - 1] : 0;
  for (int i = b; i < e; ++i) {
    offsets[i] = run; cursor[i] = run; run += counts[i];
  }
  if (tid == 1023) offsets[Nn] = part[1023];
}

// ---------------------------------------------------------------------------
// CSR fill: edge_ids grouped by dst.
// ---------------------------------------------------------------------------
__global__ __launch_bounds__(256) void fill_kernel(
    const int* __restrict__ dst, int* __restrict__ cursor,
    int* __restrict__ edge_ids, int E_)
{
  int e = blockIdx.x * 256 + threadIdx.x;
  if (e < E_) {
    int p = atomicAdd(&cursor[dst[e]], 1);
    edge_ids[p] = e;
  }
}

// ---------------------------------------------------------------------------
// Per-(node,head): softmax over incoming edges + weighted gather of z[src],
// epilogue out = h + relu(hs + agg).  One 256-thread block per (n, head);
// thread t owns channel t.  No atomics.  Gather loop 4-way unrolled: 4
// independent z-row loads in flight (round-4 counters: latency-bound —
// VALUBusy 20%, HBM 21%, occupancy 88%).
// ---------------------------------------------------------------------------
__global__ __launch_bounds__(256) void agg_kernel(
    const float* __restrict__ zbuf, const float* __restrict__ e_score,
    const int* __restrict__ src, const int* __restrict__ offsets,
    const int* __restrict__ edge_ids, const float* __restrict__ hin,
    float* __restrict__ out, int Nn, int E_)
{
  const int n = blockIdx.x, head = blockIdx.y;
  const int tid = threadIdx.x, lane = tid & 63, w = tid >> 6;
  __shared__ float red[4];
  const int s = offsets[n];
  const int deg = offsets[n + 1] - s;
  const float* sc = e_score + (size_t)head * E_;

  float lm = -INFINITY;
  for (int i = tid; i < deg; i += 256) lm = fmaxf(lm, sc[edge_ids[s + i]]);
#pragma unroll
  for (int off = 32; off; off >>= 1) lm = fmaxf(lm, __shfl_down(lm, off));
  if (lane == 0) red[w] = lm;
  __syncthreads();
  float m = fmaxf(fmaxf(red[0], red[1]), fmaxf(red[2], red[3]));
  if (!isfinite(m)) m = 0.f;          // empty segment -> segment_max fixup
  __syncthreads();

  float ls = 0.f;
  for (int i = tid; i < deg; i += 256) ls += __expf(sc[edge_ids[s + i]] - m);
#pragma unroll
  for (int off = 32; off; off >>= 1) ls += __shfl_down(ls, off);
  if (lane == 0) red[w] = ls;
  __syncthreads();
  float den = red[0] + red[1] + red[2] + red[3];
  float inv = 1.f / fmaxf(den, 1e-16f);

  float acc = 0.f;
  const float* zh = zbuf + (size_t)head * Nn * D;
  int i = 0;
  for (; i + 3 < deg; i += 4) {
    int e0 = edge_ids[s + i], e1 = edge_ids[s + i + 1];
    int e2 = edge_ids[s + i + 2], e3 = edge_ids[s + i + 3];
    int s0 = src[e0], s1 = src[e1], s2 = src[e2], s3 = src[e3];
    float w0 = __expf(sc[e0] - m), w1 = __expf(sc[e1] - m);
    float w2 = __expf(sc[e2] - m), w3 = __expf(sc[e3] - m);
    float z0 = zh[(size_t)s0 * D + tid];
    float z1 = zh[(size_t)s1 * D + tid];
    float z2 = zh[(size_t)s2 * D + tid];
    float z3 = zh[(size_t)s3 * D + tid];
    acc += w0 * z0 + w1 * z1 + w2 * z2 + w3 * z3;
  }
  for (; i < deg; ++i) {
    int e0 = edge_ids[s + i];
    acc += __expf(sc[e0] - m) * zh[(size_t)src[e0] * D + tid];
  }
  acc *= inv;
  size_t o = (size_t)n * (HD * D) + head * D + tid;
  out[o] = hin[(size_t)n * D + tid] + fmaxf(out[o] + acc, 0.f);
}

// ---------------------------------------------------------------------------
extern "C" void kernel_launch(void* const* d_in, const int* in_sizes, int n_in,
                              void* d_out, int out_size, void* d_ws, size_t ws_size,
                              hipStream_t stream) {
  const float* hin    = (const float*)d_in[0];
  const float* edge_w = (const float*)d_in[1];
  const int*   src    = (const int*)d_in[2];
  const int*   dst    = (const int*)d_in[3];
  const float* Wself  = (const float*)d_in[4];
  const float* Wfunc  = (const float*)d_in[5];
  const float* attn   = (const float*)d_in[6];
  float* out = (float*)d_out;

  const int Nn = in_sizes[0] / D;   // 20000
  const int E_ = in_sizes[2];       // 320000

  // workspace layout (67.28 MB total == round-4's proven footprint).
  // Wsp (1.57 MB, live: splitW -> gemm) ALIASES e_score (3.84 MB, live:
  // edge -> agg); stream order separates the lifetimes.
  float* zbuf = (float*)d_ws;                        // HD*Nn*D fp32
  float* zs   = zbuf + (size_t)HD * Nn * D;          // HD*Nn
  float* zd   = zs + (size_t)HD * Nn;                // HD*Nn
  float* un   = zd + (size_t)HD * Nn;                // union base
  ushort* Wsp     = (ushort*)un;                     // 6*2*65536 ushort
  float*  e_score = un;                              // HD*E fp32
  int* counts   = (int*)(un + (size_t)HD * E_);      // Nn
  int* offsets  = counts + Nn;                       // Nn+1
  int* cursor   = offsets + Nn + 1;                  // Nn
  int* edge_ids = cursor + Nn;                       // E

  hipMemsetAsync(counts, 0, (size_t)Nn * sizeof(int), stream);

  splitW_kernel<<<1536, 256, 0, stream>>>(Wself, Wfunc, Wsp);

  dim3 ggrid((Nn + 127) / 128, 6);
  gemm_mfma_kernel<<<ggrid, 256, 0, stream>>>(hin, Wsp, out, zbuf, Nn);

  int nwave = Nn * HD;
  node_dot_kernel<<<(nwave + 3) / 4, 256, 0, stream>>>(zbuf, attn, zs, zd, Nn);

  edge_kernel<<<(E_ + 3) / 4, 256, 0, stream>>>(edge_w, attn, src, dst, zs, zd,
                                                e_score, counts, E_, Nn);

  int chunk = (Nn + 1023) / 1024;
  scan_kernel<<<1, 1024, 0, stream>>>(counts, offsets, cursor, Nn, chunk);

  fill_kernel<<<(E_ + 255) / 256, 256, 0, stream>>>(dst, cursor, edge_ids, E_);

  dim3 agrid(Nn, HD);
  agg_kernel<<<agrid, 256, 0, stream>>>(zbuf, e_score, src, offsets, edge_ids,
                                        hin, out, Nn, E_);
}